// Round 1
// baseline (5011.951 us; speedup 1.0000x reference)
//
#include <hip/hip_runtime.h>
#include <hip/hip_bf16.h>
#include <math.h>

typedef __bf16 bf16_t;
typedef __attribute__((ext_vector_type(8))) __bf16 bf16x8;
typedef __attribute__((ext_vector_type(4))) __bf16 bf16x4;
typedef __attribute__((ext_vector_type(4))) float f32x4;

static constexpr int B_ = 16, C_ = 16, T_ = 128, D_ = 256, H_ = 8;
static constexpr int L_ = 12, FF_ = 1024;
static constexpr int NSEQ = C_ * T_ + 1;      // 2049
static constexpr int M_ = B_ * NSEQ;          // 32784
static constexpr float EPS_ = 1e-5f;

__device__ __forceinline__ float wave_sum(float s) {
    #pragma unroll
    for (int o = 1; o < 64; o <<= 1) s += __shfl_xor(s, o);
    return s;
}

// ---------------- weight conversion ----------------
// Wq/Wk/Wv [L][256][256] (row=k, col=n) -> wqkv_t [L][768][256] bf16 (row=n, col=k)
__global__ void conv_qkv(const float* __restrict__ Wq, const float* __restrict__ Wk,
                         const float* __restrict__ Wv, bf16_t* __restrict__ out) {
    size_t i = (size_t)blockIdx.x * 256 + threadIdx.x;
    size_t tot = (size_t)L_ * 768 * 256;
    if (i >= tot) return;
    int k = i & 255;
    int n = (i >> 8) % 768;
    int l = i / (768 * 256);
    const float* src = (n < 256) ? Wq : (n < 512) ? Wk : Wv;
    int nn = n & 255;
    out[i] = (bf16_t)src[((size_t)l * 256 + k) * 256 + nn];
}

// W [L][R][Cc] -> out [L][Cc][R] bf16 (transpose last two dims)
__global__ void conv_t(const float* __restrict__ W, bf16_t* __restrict__ out, int R, int Cc) {
    size_t i = (size_t)blockIdx.x * 256 + threadIdx.x;
    size_t tot = (size_t)L_ * R * Cc;
    if (i >= tot) return;
    int r = i % R;
    int c = (i / R) % Cc;
    int l = i / ((size_t)R * Cc);
    out[i] = (bf16_t)W[((size_t)l * R + r) * Cc + c];
}

// ---------------- embedding ----------------
__global__ void embed_kernel(const int* __restrict__ x, const float* __restrict__ emb,
                             const float* __restrict__ ch, const float* __restrict__ cls,
                             float* __restrict__ h) {
    int wave = threadIdx.x >> 6, lane = threadIdx.x & 63;
    int row = blockIdx.x * 4 + wave;          // [0, M_)
    int d0 = lane * 4;
    float4 o;
    int b = row / NSEQ, n = row % NSEQ;
    if (n == 0) {
        o = *(const float4*)(cls + d0);
    } else {
        int idx = n - 1;
        int c = idx / T_, t = idx % T_;
        int tok = x[(b * C_ + c) * T_ + t];
        float4 ev = *(const float4*)(emb + (size_t)tok * 256 + d0);
        float4 cv = *(const float4*)(ch + c * 256 + d0);
        const float kdiv = -0.03597789207803197f;   // -ln(10000)/256
        float f0 = __expf(d0 * kdiv);
        float f2 = __expf((d0 + 2) * kdiv);
        float a0 = t * f0, a2 = t * f2;
        o.x = ev.x + cv.x + sinf(a0);
        o.y = ev.y + cv.y + cosf(a0);
        o.z = ev.z + cv.z + sinf(a2);
        o.w = ev.w + cv.w + cosf(a2);
    }
    *(float4*)(h + (size_t)row * 256 + d0) = o;
}

// ---------------- layer norm -> bf16 ----------------
__global__ void ln_kernel(const float* __restrict__ h, const float* __restrict__ g,
                          const float* __restrict__ bb, bf16_t* __restrict__ out) {
    int wave = threadIdx.x >> 6, lane = threadIdx.x & 63;
    int row = blockIdx.x * 4 + wave;
    const float* xp = h + (size_t)row * 256;
    int d0 = lane * 4;
    float4 v = *(const float4*)(xp + d0);
    float s = wave_sum(v.x + v.y + v.z + v.w);
    float mean = s * (1.f / 256.f);
    float4 d;
    d.x = v.x - mean; d.y = v.y - mean; d.z = v.z - mean; d.w = v.w - mean;
    float q = wave_sum(d.x * d.x + d.y * d.y + d.z * d.z + d.w * d.w);
    float rs = rsqrtf(q * (1.f / 256.f) + EPS_);
    float4 gv = *(const float4*)(g + d0);
    float4 bv = *(const float4*)(bb + d0);
    bf16x4 o4;
    o4[0] = (bf16_t)(d.x * rs * gv.x + bv.x);
    o4[1] = (bf16_t)(d.y * rs * gv.y + bv.y);
    o4[2] = (bf16_t)(d.z * rs * gv.z + bv.z);
    o4[3] = (bf16_t)(d.w * rs * gv.w + bv.w);
    *(bf16x4*)(out + (size_t)row * 256 + d0) = o4;
}

// ---------------- generic bf16 MFMA GEMM ----------------
// A [M][K] bf16, Bt [N][K] bf16, out per EPI:
//  EPI 0: Cf[r*N+c] = acc (+bias)
//  EPI 1: Cf[r*N+c] += acc + bias     (residual add into fp32 h)
//  EPI 2: Cb[r*N+c] = bf16(gelu(acc + bias))
template <int EPI>
__launch_bounds__(256, 2)
__global__ void gemm_bf16(const bf16_t* __restrict__ A, const bf16_t* __restrict__ Bt,
                          float* __restrict__ Cf, bf16_t* __restrict__ Cb,
                          const float* __restrict__ bias, int M, int N, int K) {
    constexpr int BM = 128, BN = 128, BK = 64, SA = 72;
    __shared__ bf16_t As[BM * SA];
    __shared__ bf16_t Bs[BN * SA];
    int tid = threadIdx.x;
    int wave = tid >> 6, lane = tid & 63;
    int wr = wave >> 1, wc = wave & 1;
    int row0 = blockIdx.x * BM, col0 = blockIdx.y * BN;

    f32x4 acc[4][4] = {};

    for (int k0 = 0; k0 < K; k0 += BK) {
        #pragma unroll
        for (int it = 0; it < 4; ++it) {
            int idx = it * 256 + tid;
            int r = idx >> 3, c = (idx & 7) * 8;
            uint4 va = {0u, 0u, 0u, 0u};
            int gr = row0 + r;
            if (gr < M) va = *(const uint4*)(A + (size_t)gr * K + k0 + c);
            *(uint4*)(&As[r * SA + c]) = va;
            uint4 vb = {0u, 0u, 0u, 0u};
            int gn = col0 + r;
            if (gn < N) vb = *(const uint4*)(Bt + (size_t)gn * K + k0 + c);
            *(uint4*)(&Bs[r * SA + c]) = vb;
        }
        __syncthreads();
        #pragma unroll
        for (int kk = 0; kk < 2; ++kk) {
            bf16x8 af[4], bfr[4];
            #pragma unroll
            for (int m = 0; m < 4; ++m) {
                int r = wr * 64 + m * 16 + (lane & 15);
                af[m] = *(const bf16x8*)(&As[r * SA + kk * 32 + (lane >> 4) * 8]);
            }
            #pragma unroll
            for (int n = 0; n < 4; ++n) {
                int r = wc * 64 + n * 16 + (lane & 15);
                bfr[n] = *(const bf16x8*)(&Bs[r * SA + kk * 32 + (lane >> 4) * 8]);
            }
            #pragma unroll
            for (int m = 0; m < 4; ++m)
                #pragma unroll
                for (int n = 0; n < 4; ++n)
                    acc[m][n] = __builtin_amdgcn_mfma_f32_16x16x32_bf16(af[m], bfr[n], acc[m][n], 0, 0, 0);
        }
        __syncthreads();
    }

    #pragma unroll
    for (int m = 0; m < 4; ++m) {
        int rbase = row0 + wr * 64 + m * 16 + ((lane >> 4) << 2);
        #pragma unroll
        for (int n = 0; n < 4; ++n) {
            int c = col0 + wc * 64 + n * 16 + (lane & 15);
            float bv = bias ? bias[c] : 0.f;
            #pragma unroll
            for (int i = 0; i < 4; ++i) {
                int r = rbase + i;
                if (r < M) {
                    float v = acc[m][n][i] + bv;
                    if (EPI == 0) {
                        Cf[(size_t)r * N + c] = v;
                    } else if (EPI == 1) {
                        Cf[(size_t)r * N + c] += v;
                    } else {
                        float gl = 0.5f * v * (1.f + erff(v * 0.70710678118654752f));
                        Cb[(size_t)r * N + c] = (bf16_t)gl;
                    }
                }
            }
        }
    }
}

// ---------------- q softmax (over dh=32) + scale ----------------
__global__ void qsm_kernel(float* __restrict__ qkv) {
    int t = blockIdx.x * 256 + threadIdx.x;
    if (t >= M_ * H_) return;
    int row = t >> 3, hh = t & 7;
    float* q = qkv + (size_t)row * 768 + hh * 32;
    float v[32];
    float m = -1e30f;
    #pragma unroll
    for (int i = 0; i < 32; ++i) { v[i] = q[i]; m = fmaxf(m, v[i]); }
    float s = 0.f;
    #pragma unroll
    for (int i = 0; i < 32; ++i) { v[i] = __expf(v[i] - m); s += v[i]; }
    float inv = 0.17677669529663689f / s;   // dh^-0.5 / sum
    #pragma unroll
    for (int i = 0; i < 32; ++i) q[i] = v[i] * inv;
}

// ---------------- k column max (over n) ----------------
__global__ void kmax_kernel(const float* __restrict__ qkv, float* __restrict__ colmax) {
    int bh = blockIdx.x;                 // b*8+h
    int b = bh >> 3, hh = bh & 7;
    int c = threadIdx.x & 31, stripe = threadIdx.x >> 5;
    const float* base = qkv + (size_t)b * NSEQ * 768 + 256 + hh * 32;
    float m = -1e30f;
    for (int n = stripe; n < NSEQ; n += 8)
        m = fmaxf(m, base[(size_t)n * 768 + c]);
    __shared__ float red[8][32];
    red[stripe][c] = m;
    __syncthreads();
    if (threadIdx.x < 32) {
        float mm = red[0][c];
        #pragma unroll
        for (int s2 = 1; s2 < 8; ++s2) mm = fmaxf(mm, red[s2][c]);
        colmax[bh * 32 + c] = mm;
    }
}

// ---------------- ctx partial: ctx_raw[d][e] = sum_n exp(k-max)*v ; colsum[d] ----------------
__global__ void ctx_kernel(const float* __restrict__ qkv, const float* __restrict__ colmax,
                           float* __restrict__ ctx_part, float* __restrict__ colsum_part) {
    int blk = blockIdx.x;                // bh*8 + s
    int bh = blk >> 3, s = blk & 7;
    int b = bh >> 3, hh = bh & 7;
    int n0 = s * 257, n1 = min(n0 + 257, NSEQ);
    int d = threadIdx.x & 31, eg = threadIdx.x >> 5;
    float maxd = colmax[bh * 32 + d];
    float acc[4] = {0.f, 0.f, 0.f, 0.f};
    float ksum = 0.f;
    __shared__ float ks[64][32];
    __shared__ float vs[64][32];
    const float* kbase = qkv + (size_t)b * NSEQ * 768 + 256 + hh * 32;
    const float* vbase = kbase + 256;
    int lr = threadIdx.x >> 2, lc = (threadIdx.x & 3) * 8;
    for (int c0 = n0; c0 < n1; c0 += 64) {
        int rows = min(64, n1 - c0);
        if (lr < rows) {
            const float* kp = kbase + (size_t)(c0 + lr) * 768 + lc;
            *(float4*)&ks[lr][lc] = *(const float4*)kp;
            *(float4*)&ks[lr][lc + 4] = *(const float4*)(kp + 4);
            const float* vp = vbase + (size_t)(c0 + lr) * 768 + lc;
            *(float4*)&vs[lr][lc] = *(const float4*)vp;
            *(float4*)&vs[lr][lc + 4] = *(const float4*)(vp + 4);
        }
        __syncthreads();
        for (int r = 0; r < rows; ++r) {
            float ek = __expf(ks[r][d] - maxd);
            if (eg == 0) ksum += ek;
            const float* vr = &vs[r][eg * 4];
            acc[0] += ek * vr[0]; acc[1] += ek * vr[1];
            acc[2] += ek * vr[2]; acc[3] += ek * vr[3];
        }
        __syncthreads();
    }
    float* cp = ctx_part + ((size_t)blk * 32 + d) * 32 + eg * 4;
    cp[0] = acc[0]; cp[1] = acc[1]; cp[2] = acc[2]; cp[3] = acc[3];
    if (eg == 0) colsum_part[blk * 32 + d] = ksum;
}

// ---------------- o = q @ ctx  -> bf16 [M][256] ----------------
__global__ void o_kernel(const float* __restrict__ qkv, const float* __restrict__ ctx_part,
                         const float* __restrict__ colsum_part, bf16_t* __restrict__ o) {
    int bh = blockIdx.x, b = bh >> 3, hh = bh & 7;
    int chunk = blockIdx.y;
    __shared__ float ctx[1024];
    __shared__ float csum[32];
    int t = threadIdx.x;
    if (t < 32) {
        float s = 0.f;
        #pragma unroll
        for (int ss = 0; ss < 8; ++ss) s += colsum_part[(bh * 8 + ss) * 32 + t];
        csum[t] = s;
    }
    __syncthreads();
    for (int i = t; i < 1024; i += 256) {
        float s = 0.f;
        #pragma unroll
        for (int ss = 0; ss < 8; ++ss) s += ctx_part[(size_t)(bh * 8 + ss) * 1024 + i];
        ctx[i] = s / csum[i >> 5];
    }
    __syncthreads();
    int e = t & 31, rg = t >> 5;
    int n0 = chunk * 228, n1 = min(n0 + 228, NSEQ);
    for (int n = n0 + rg; n < n1; n += 8) {
        const float* q = qkv + (size_t)(b * NSEQ + n) * 768 + hh * 32;
        float s = 0.f;
        #pragma unroll
        for (int dd = 0; dd < 32; ++dd) s += q[dd] * ctx[dd * 32 + e];
        o[(size_t)(b * NSEQ + n) * 256 + hh * 32 + e] = (bf16_t)s;
    }
}

// ---------------- classifier head ----------------
__global__ void head_kernel(const float* __restrict__ h, const float* __restrict__ Wh,
                            const float* __restrict__ bh, float* __restrict__ out) {
    int t = threadIdx.x;
    if (t < 80) {
        int b = t / 5, c = t % 5;
        const float* xp = h + (size_t)b * NSEQ * 256;
        float s = bh[c];
        for (int dd = 0; dd < 256; ++dd) s += xp[dd] * Wh[dd * 5 + c];
        out[t] = s;
    }
}

extern "C" void kernel_launch(void* const* d_in, const int* in_sizes, int n_in,
                              void* d_out, int out_size, void* d_ws, size_t ws_size,
                              hipStream_t stream) {
    const int*   x    = (const int*)d_in[0];
    const float* emb  = (const float*)d_in[1];
    const float* ch   = (const float*)d_in[2];
    const float* cls  = (const float*)d_in[3];
    const float* Wq   = (const float*)d_in[4];
    const float* Wk   = (const float*)d_in[5];
    const float* Wv   = (const float*)d_in[6];
    const float* Wo   = (const float*)d_in[7];
    const float* bo   = (const float*)d_in[8];
    const float* g1   = (const float*)d_in[9];
    const float* b1   = (const float*)d_in[10];
    const float* W1   = (const float*)d_in[11];
    const float* bf1  = (const float*)d_in[12];
    const float* W2   = (const float*)d_in[13];
    const float* bf2  = (const float*)d_in[14];
    const float* g2   = (const float*)d_in[15];
    const float* b2   = (const float*)d_in[16];
    const float* Wh   = (const float*)d_in[17];
    const float* bh   = (const float*)d_in[18];

    char* ws = (char*)d_ws;
    size_t off = 0;
    float*  h      = (float*)(ws + off);  off += (size_t)M_ * 256 * 4;          // 33,570,816
    bf16_t* yn     = (bf16_t*)(ws + off); off += (size_t)M_ * 256 * 2;          // 16,785,408
    float*  qkv    = (float*)(ws + off);
    bf16_t* f1     = (bf16_t*)(ws + off); off += (size_t)M_ * 768 * 4;          // 100,712,448 (f1 aliases qkv)
    float*  ctxp   = (float*)(ws + off);  off += (size_t)16 * 8 * 8 * 1024 * 4; // 4,194,304
    float*  csump  = (float*)(ws + off);  off += (size_t)16 * 8 * 8 * 32 * 4;   // 131,072
    float*  cmax   = (float*)(ws + off);  off += (size_t)16 * 8 * 32 * 4;       // 16,384
    bf16_t* wqkv_t = (bf16_t*)(ws + off); off += (size_t)L_ * 768 * 256 * 2;    // 4,718,592
    bf16_t* wo_t   = (bf16_t*)(ws + off); off += (size_t)L_ * 256 * 256 * 2;    // 1,572,864
    bf16_t* w1_t   = (bf16_t*)(ws + off); off += (size_t)L_ * 1024 * 256 * 2;   // 6,291,456
    bf16_t* w2_t   = (bf16_t*)(ws + off); off += (size_t)L_ * 256 * 1024 * 2;   // 6,291,456
    (void)ws_size; (void)in_sizes; (void)n_in; (void)out_size;

    // weights -> bf16 transposed [N][K]
    conv_qkv<<<9216, 256, 0, stream>>>(Wq, Wk, Wv, wqkv_t);
    conv_t<<<3072, 256, 0, stream>>>(Wo, wo_t, 256, 256);
    conv_t<<<12288, 256, 0, stream>>>(W1, w1_t, 256, 1024);
    conv_t<<<12288, 256, 0, stream>>>(W2, w2_t, 1024, 256);

    embed_kernel<<<M_ / 4, 256, 0, stream>>>(x, emb, ch, cls, h);

    for (int l = 0; l < L_; ++l) {
        ln_kernel<<<M_ / 4, 256, 0, stream>>>(h, g1 + l * 256, b1 + l * 256, yn);
        gemm_bf16<0><<<dim3(257, 6), 256, 0, stream>>>(yn, wqkv_t + (size_t)l * 768 * 256,
                                                       qkv, nullptr, nullptr, M_, 768, 256);
        qsm_kernel<<<1025, 256, 0, stream>>>(qkv);
        kmax_kernel<<<128, 256, 0, stream>>>(qkv, cmax);
        ctx_kernel<<<1024, 256, 0, stream>>>(qkv, cmax, ctxp, csump);
        o_kernel<<<dim3(128, 9), 256, 0, stream>>>(qkv, ctxp, csump, yn);
        gemm_bf16<1><<<dim3(257, 2), 256, 0, stream>>>(yn, wo_t + (size_t)l * 256 * 256,
                                                       h, nullptr, bo + l * 256, M_, 256, 256);
        ln_kernel<<<M_ / 4, 256, 0, stream>>>(h, g2 + l * 256, b2 + l * 256, yn);
        gemm_bf16<2><<<dim3(257, 8), 256, 0, stream>>>(yn, w1_t + (size_t)l * 1024 * 256,
                                                       nullptr, f1, bf1 + l * 1024, M_, 1024, 256);
        gemm_bf16<1><<<dim3(257, 2), 256, 0, stream>>>(f1, w2_t + (size_t)l * 256 * 1024,
                                                       h, nullptr, bf2 + l * 256, M_, 256, 1024);
    }

    head_kernel<<<1, 128, 0, stream>>>(h, Wh, bh, (float*)d_out);
}

// Round 2
// 4550.381 us; speedup vs baseline: 1.1014x; 1.1014x over previous
//
#include <hip/hip_runtime.h>
#include <hip/hip_bf16.h>
#include <math.h>

typedef __bf16 bf16_t;
typedef __attribute__((ext_vector_type(8))) __bf16 bf16x8;
typedef __attribute__((ext_vector_type(4))) __bf16 bf16x4;
typedef __attribute__((ext_vector_type(4))) float f32x4;

static constexpr int B_ = 16, C_ = 16, T_ = 128, D_ = 256, H_ = 8;
static constexpr int L_ = 12, FF_ = 1024;
static constexpr int NSEQ = C_ * T_ + 1;      // 2049
static constexpr int M_ = B_ * NSEQ;          // 32784
static constexpr int MPAD = 32896;            // 257*128, GEMM-A row padding
static constexpr float EPS_ = 1e-5f;

__device__ __forceinline__ float wave_sum(float s) {
    #pragma unroll
    for (int o = 1; o < 64; o <<= 1) s += __shfl_xor(s, o);
    return s;
}

__device__ __forceinline__ void gload_lds16(const bf16_t* g, bf16_t* l) {
    __builtin_amdgcn_global_load_lds(
        (const __attribute__((address_space(1))) unsigned int*)(g),
        (__attribute__((address_space(3))) unsigned int*)(l), 16, 0, 0);
}

// ---------------- weight conversion ----------------
__global__ void conv_qkv(const float* __restrict__ Wq, const float* __restrict__ Wk,
                         const float* __restrict__ Wv, bf16_t* __restrict__ out) {
    size_t i = (size_t)blockIdx.x * 256 + threadIdx.x;
    size_t tot = (size_t)L_ * 768 * 256;
    if (i >= tot) return;
    int k = i & 255;
    int n = (i >> 8) % 768;
    int l = i / (768 * 256);
    const float* src = (n < 256) ? Wq : (n < 512) ? Wk : Wv;
    int nn = n & 255;
    out[i] = (bf16_t)src[((size_t)l * 256 + k) * 256 + nn];
}

__global__ void conv_t(const float* __restrict__ W, bf16_t* __restrict__ out, int R, int Cc) {
    size_t i = (size_t)blockIdx.x * 256 + threadIdx.x;
    size_t tot = (size_t)L_ * R * Cc;
    if (i >= tot) return;
    int r = i % R;
    int c = (i / R) % Cc;
    int l = i / ((size_t)R * Cc);
    out[i] = (bf16_t)W[((size_t)l * R + r) * Cc + c];
}

// ---------------- embedding ----------------
__global__ void embed_kernel(const int* __restrict__ x, const float* __restrict__ emb,
                             const float* __restrict__ ch, const float* __restrict__ cls,
                             float* __restrict__ h) {
    int wave = threadIdx.x >> 6, lane = threadIdx.x & 63;
    int row = blockIdx.x * 4 + wave;
    int d0 = lane * 4;
    float4 o;
    int b = row / NSEQ, n = row % NSEQ;
    if (n == 0) {
        o = *(const float4*)(cls + d0);
    } else {
        int idx = n - 1;
        int c = idx / T_, t = idx % T_;
        int tok = x[(b * C_ + c) * T_ + t];
        float4 ev = *(const float4*)(emb + (size_t)tok * 256 + d0);
        float4 cv = *(const float4*)(ch + c * 256 + d0);
        const float kdiv = -0.03597789207803197f;   // -ln(10000)/256
        float f0 = __expf(d0 * kdiv);
        float f2 = __expf((d0 + 2) * kdiv);
        float a0 = t * f0, a2 = t * f2;
        o.x = ev.x + cv.x + sinf(a0);
        o.y = ev.y + cv.y + cosf(a0);
        o.z = ev.z + cv.z + sinf(a2);
        o.w = ev.w + cv.w + cosf(a2);
    }
    *(float4*)(h + (size_t)row * 256 + d0) = o;
}

// ---------------- layer norm -> bf16 ----------------
__global__ void ln_kernel(const float* __restrict__ h, const float* __restrict__ g,
                          const float* __restrict__ bb, bf16_t* __restrict__ out) {
    int wave = threadIdx.x >> 6, lane = threadIdx.x & 63;
    int row = blockIdx.x * 4 + wave;
    const float* xp = h + (size_t)row * 256;
    int d0 = lane * 4;
    float4 v = *(const float4*)(xp + d0);
    float s = wave_sum(v.x + v.y + v.z + v.w);
    float mean = s * (1.f / 256.f);
    float4 d;
    d.x = v.x - mean; d.y = v.y - mean; d.z = v.z - mean; d.w = v.w - mean;
    float q = wave_sum(d.x * d.x + d.y * d.y + d.z * d.z + d.w * d.w);
    float rs = rsqrtf(q * (1.f / 256.f) + EPS_);
    float4 gv = *(const float4*)(g + d0);
    float4 bv = *(const float4*)(bb + d0);
    bf16x4 o4;
    o4[0] = (bf16_t)(d.x * rs * gv.x + bv.x);
    o4[1] = (bf16_t)(d.y * rs * gv.y + bv.y);
    o4[2] = (bf16_t)(d.z * rs * gv.z + bv.z);
    o4[3] = (bf16_t)(d.w * rs * gv.w + bv.w);
    *(bf16x4*)(out + (size_t)row * 256 + d0) = o4;
}

// ---------------- MFMA GEMM, global_load_lds staging (m97 structure) ----------------
// A [Mpad][K] bf16, Bt [N][K] bf16.
//  EPI 0: Cb = bf16(acc)                  (no bias)
//  EPI 1: Cf += acc + bias                (residual into fp32 h)
//  EPI 2: Cb = bf16(gelu(acc + bias))
template <int EPI>
__launch_bounds__(256)
__global__ void gemm_bf16(const bf16_t* __restrict__ A, const bf16_t* __restrict__ Bt,
                          float* __restrict__ Cf, bf16_t* __restrict__ Cb,
                          const float* __restrict__ bias, int M, int N, int K) {
    constexpr int BM = 128, BN = 128, BK = 64;
    __shared__ bf16_t As[BM * BK];
    __shared__ bf16_t Bs[BN * BK];
    int tid = threadIdx.x;
    int wave = tid >> 6, lane = tid & 63;
    int wr = wave >> 1, wc = wave & 1;
    int row0 = blockIdx.x * BM, col0 = blockIdx.y * BN;
    const bf16_t* Ab = A + (size_t)row0 * K;
    const bf16_t* Bb = Bt + (size_t)col0 * K;
    int lrow = lane >> 3, lcol = (lane & 7) * 8;

    f32x4 acc[4][4] = {};

    for (int k0 = 0; k0 < K; k0 += BK) {
        #pragma unroll
        for (int s = 0; s < 4; ++s) {
            int r = s * 32 + wave * 8;
            gload_lds16(Ab + (size_t)(r + lrow) * K + k0 + lcol, &As[r * BK]);
            gload_lds16(Bb + (size_t)(r + lrow) * K + k0 + lcol, &Bs[r * BK]);
        }
        __syncthreads();
        #pragma unroll
        for (int kk = 0; kk < 2; ++kk) {
            bf16x8 af[4], bfr[4];
            #pragma unroll
            for (int m = 0; m < 4; ++m) {
                int r = wr * 64 + m * 16 + (lane & 15);
                af[m] = *(const bf16x8*)(&As[r * BK + kk * 32 + (lane >> 4) * 8]);
            }
            #pragma unroll
            for (int n = 0; n < 4; ++n) {
                int r = wc * 64 + n * 16 + (lane & 15);
                bfr[n] = *(const bf16x8*)(&Bs[r * BK + kk * 32 + (lane >> 4) * 8]);
            }
            #pragma unroll
            for (int m = 0; m < 4; ++m)
                #pragma unroll
                for (int n = 0; n < 4; ++n)
                    acc[m][n] = __builtin_amdgcn_mfma_f32_16x16x32_bf16(af[m], bfr[n], acc[m][n], 0, 0, 0);
        }
        __syncthreads();
    }

    #pragma unroll
    for (int m = 0; m < 4; ++m) {
        int rbase = row0 + wr * 64 + m * 16 + ((lane >> 4) << 2);
        #pragma unroll
        for (int n = 0; n < 4; ++n) {
            int c = col0 + wc * 64 + n * 16 + (lane & 15);
            float bv = (EPI != 0) ? bias[c] : 0.f;
            #pragma unroll
            for (int i = 0; i < 4; ++i) {
                int r = rbase + i;
                if (r < M) {
                    float v = acc[m][n][i] + bv;
                    if (EPI == 0) {
                        Cb[(size_t)r * N + c] = (bf16_t)v;
                    } else if (EPI == 1) {
                        Cf[(size_t)r * N + c] += v;
                    } else {
                        float gl = 0.5f * v * (1.f + erff(v * 0.70710678118654752f));
                        Cb[(size_t)r * N + c] = (bf16_t)gl;
                    }
                }
            }
        }
    }
}

// ---------------- k column max (over n) ----------------
__global__ void kmax_kernel(const bf16_t* __restrict__ qkv, float* __restrict__ colmax) {
    int bh = blockIdx.x;                 // b*8+h
    int b = bh >> 3, hh = bh & 7;
    int c = threadIdx.x & 31, stripe = threadIdx.x >> 5;
    const bf16_t* base = qkv + (size_t)b * NSEQ * 768 + 256 + hh * 32;
    float m = -1e30f;
    for (int n = stripe; n < NSEQ; n += 8)
        m = fmaxf(m, (float)base[(size_t)n * 768 + c]);
    __shared__ float red[8][32];
    red[stripe][c] = m;
    __syncthreads();
    if (threadIdx.x < 32) {
        float mm = red[0][c];
        #pragma unroll
        for (int s2 = 1; s2 < 8; ++s2) mm = fmaxf(mm, red[s2][c]);
        colmax[bh * 32 + c] = mm;
    }
}

// ---------------- ctx partial: sum_n exp(k-max)*v ; colsum ----------------
__global__ void ctx_kernel(const bf16_t* __restrict__ qkv, const float* __restrict__ colmax,
                           float* __restrict__ ctx_part, float* __restrict__ colsum_part) {
    int blk = blockIdx.x;                // bh*8 + s
    int bh = blk >> 3, s = blk & 7;
    int b = bh >> 3, hh = bh & 7;
    int n0 = s * 257, n1 = min(n0 + 257, NSEQ);
    int d = threadIdx.x & 31, eg = threadIdx.x >> 5;
    float maxd = colmax[bh * 32 + d];
    float acc[4] = {0.f, 0.f, 0.f, 0.f};
    float ksum = 0.f;
    __shared__ float ks[64][32];
    __shared__ float vs[64][32];
    const bf16_t* kbase = qkv + (size_t)b * NSEQ * 768 + 256 + hh * 32;
    const bf16_t* vbase = kbase + 256;
    int lr = threadIdx.x >> 2, lc = (threadIdx.x & 3) * 8;
    for (int c0 = n0; c0 < n1; c0 += 64) {
        int rows = min(64, n1 - c0);
        if (lr < rows) {
            bf16x8 kv8 = *(const bf16x8*)(kbase + (size_t)(c0 + lr) * 768 + lc);
            bf16x8 vv8 = *(const bf16x8*)(vbase + (size_t)(c0 + lr) * 768 + lc);
            #pragma unroll
            for (int j = 0; j < 8; ++j) {
                ks[lr][lc + j] = (float)kv8[j];
                vs[lr][lc + j] = (float)vv8[j];
            }
        }
        __syncthreads();
        for (int r = 0; r < rows; ++r) {
            float ek = __expf(ks[r][d] - maxd);
            if (eg == 0) ksum += ek;
            const float* vr = &vs[r][eg * 4];
            acc[0] += ek * vr[0]; acc[1] += ek * vr[1];
            acc[2] += ek * vr[2]; acc[3] += ek * vr[3];
        }
        __syncthreads();
    }
    float* cp = ctx_part + ((size_t)blk * 32 + d) * 32 + eg * 4;
    cp[0] = acc[0]; cp[1] = acc[1]; cp[2] = acc[2]; cp[3] = acc[3];
    if (eg == 0) colsum_part[blk * 32 + d] = ksum;
}

// ---------------- o = softmax(q)*scale @ ctx  -> bf16 [M][256] ----------------
__global__ void o_kernel(const bf16_t* __restrict__ qkv, const float* __restrict__ ctx_part,
                         const float* __restrict__ colsum_part, bf16_t* __restrict__ o) {
    int bh = blockIdx.x, b = bh >> 3, hh = bh & 7;
    int chunk = blockIdx.y;
    __shared__ float ctx[1024];
    __shared__ float csum[32];
    int t = threadIdx.x;
    if (t < 32) {
        float s = 0.f;
        #pragma unroll
        for (int ss = 0; ss < 8; ++ss) s += colsum_part[(bh * 8 + ss) * 32 + t];
        csum[t] = s;
    }
    __syncthreads();
    for (int i = t; i < 1024; i += 256) {
        float s = 0.f;
        #pragma unroll
        for (int ss = 0; ss < 8; ++ss) s += ctx_part[(size_t)(bh * 8 + ss) * 1024 + i];
        ctx[i] = s / csum[i >> 5];
    }
    __syncthreads();
    int e = t & 31, grp = t >> 5;
    int n0 = chunk * 228, n1 = min(n0 + 228, NSEQ);
    for (int n = n0 + grp; n < n1; n += 8) {
        const bf16_t* q = qkv + (size_t)(b * NSEQ + n) * 768 + hh * 32;
        float qv = (float)q[e];
        float mx = qv;
        #pragma unroll
        for (int o2 = 16; o2 > 0; o2 >>= 1) mx = fmaxf(mx, __shfl_xor(mx, o2, 32));
        float ev = __expf(qv - mx);
        float sm = ev;
        #pragma unroll
        for (int o2 = 16; o2 > 0; o2 >>= 1) sm += __shfl_xor(sm, o2, 32);
        float p = ev * 0.17677669529663689f / sm;   // dh^-0.5 / sum
        float s = 0.f;
        #pragma unroll
        for (int dd = 0; dd < 32; ++dd) s += __shfl(p, dd, 32) * ctx[dd * 32 + e];
        o[(size_t)(b * NSEQ + n) * 256 + hh * 32 + e] = (bf16_t)s;
    }
}

// ---------------- classifier head ----------------
__global__ void head_kernel(const float* __restrict__ h, const float* __restrict__ Wh,
                            const float* __restrict__ bh, float* __restrict__ out) {
    int t = threadIdx.x;
    if (t < 80) {
        int b = t / 5, c = t % 5;
        const float* xp = h + (size_t)b * NSEQ * 256;
        float s = bh[c];
        for (int dd = 0; dd < 256; ++dd) s += xp[dd] * Wh[dd * 5 + c];
        out[t] = s;
    }
}

extern "C" void kernel_launch(void* const* d_in, const int* in_sizes, int n_in,
                              void* d_out, int out_size, void* d_ws, size_t ws_size,
                              hipStream_t stream) {
    const int*   x    = (const int*)d_in[0];
    const float* emb  = (const float*)d_in[1];
    const float* ch   = (const float*)d_in[2];
    const float* cls  = (const float*)d_in[3];
    const float* Wq   = (const float*)d_in[4];
    const float* Wk   = (const float*)d_in[5];
    const float* Wv   = (const float*)d_in[6];
    const float* Wo   = (const float*)d_in[7];
    const float* bo   = (const float*)d_in[8];
    const float* g1   = (const float*)d_in[9];
    const float* b1   = (const float*)d_in[10];
    const float* W1   = (const float*)d_in[11];
    const float* bf1  = (const float*)d_in[12];
    const float* W2   = (const float*)d_in[13];
    const float* bf2  = (const float*)d_in[14];
    const float* g2   = (const float*)d_in[15];
    const float* b2   = (const float*)d_in[16];
    const float* Wh   = (const float*)d_in[17];
    const float* bh   = (const float*)d_in[18];

    char* ws = (char*)d_ws;
    size_t off = 0;
    float*  h      = (float*)(ws + off);  off += (size_t)M_ * 256 * 4;            // 33,570,816
    bf16_t* yn     = (bf16_t*)(ws + off); off += (size_t)MPAD * 256 * 2;          // 16,842,752 (padded GEMM-A)
    bf16_t* qkv    = (bf16_t*)(ws + off);
    bf16_t* f1     = (bf16_t*)(ws + off); off += (size_t)MPAD * 1024 * 2;         // 67,371,008 (f1 aliases qkv, padded)
    float*  ctxp   = (float*)(ws + off);  off += (size_t)16 * 8 * 8 * 1024 * 4;   // 4,194,304
    float*  csump  = (float*)(ws + off);  off += (size_t)16 * 8 * 8 * 32 * 4;     // 131,072
    float*  cmax   = (float*)(ws + off);  off += (size_t)16 * 8 * 32 * 4;         // 16,384
    bf16_t* wqkv_t = (bf16_t*)(ws + off); off += (size_t)L_ * 768 * 256 * 2;      // 4,718,592
    bf16_t* wo_t   = (bf16_t*)(ws + off); off += (size_t)L_ * 256 * 256 * 2;      // 1,572,864
    bf16_t* w1_t   = (bf16_t*)(ws + off); off += (size_t)L_ * 1024 * 256 * 2;     // 6,291,456
    bf16_t* w2_t   = (bf16_t*)(ws + off); off += (size_t)L_ * 256 * 1024 * 2;     // 6,291,456
    (void)ws_size; (void)in_sizes; (void)n_in; (void)out_size;

    conv_qkv<<<9216, 256, 0, stream>>>(Wq, Wk, Wv, wqkv_t);
    conv_t<<<3072, 256, 0, stream>>>(Wo, wo_t, 256, 256);
    conv_t<<<12288, 256, 0, stream>>>(W1, w1_t, 256, 1024);
    conv_t<<<12288, 256, 0, stream>>>(W2, w2_t, 1024, 256);

    embed_kernel<<<M_ / 4, 256, 0, stream>>>(x, emb, ch, cls, h);

    for (int l = 0; l < L_; ++l) {
        ln_kernel<<<M_ / 4, 256, 0, stream>>>(h, g1 + l * 256, b1 + l * 256, yn);
        gemm_bf16<0><<<dim3(257, 6), 256, 0, stream>>>(yn, wqkv_t + (size_t)l * 768 * 256,
                                                       nullptr, qkv, nullptr, M_, 768, 256);
        kmax_kernel<<<128, 256, 0, stream>>>(qkv, cmax);
        ctx_kernel<<<1024, 256, 0, stream>>>(qkv, cmax, ctxp, csump);
        o_kernel<<<dim3(128, 9), 256, 0, stream>>>(qkv, ctxp, csump, yn);
        gemm_bf16<1><<<dim3(257, 2), 256, 0, stream>>>(yn, wo_t + (size_t)l * 256 * 256,
                                                       h, nullptr, bo + l * 256, M_, 256, 256);
        ln_kernel<<<M_ / 4, 256, 0, stream>>>(h, g2 + l * 256, b2 + l * 256, yn);
        gemm_bf16<2><<<dim3(257, 8), 256, 0, stream>>>(yn, w1_t + (size_t)l * 1024 * 256,
                                                       nullptr, f1, bf1 + l * 1024, M_, 1024, 256);
        gemm_bf16<1><<<dim3(257, 2), 256, 0, stream>>>(f1, w2_t + (size_t)l * 256 * 1024,
                                                       h, nullptr, bf2 + l * 256, M_, 256, 1024);
    }

    head_kernel<<<1, 128, 0, stream>>>(h, Wh, bh, (float*)d_out);
}